// Round 17
// baseline (4944.490 us; speedup 1.0000x reference)
//
#include <hip/hip_runtime.h>
#include <cstdint>
#include <cstddef>

namespace {

constexpr int TS  = 512;   // timesteps
constexpr int BB  = 1024;  // batch
constexpr int IND = 32;    // input dim
constexpr int H0D = 128;   // layer0 hidden
constexpr int H1D = 64;    // layer1 hidden
constexpr int RPW = 4;     // batch rows per WG -> 256 WGs = 1 block/CU
constexpr int S0  = 132;   // padded LDS row stride (floats) for 128-wide state
constexpr int S1  = 68;    // padded LDS row stride (floats) for 64-wide state

typedef float f32x4 __attribute__((ext_vector_type(4)));
typedef __bf16 bf16x8 __attribute__((ext_vector_type(8)));

__device__ __forceinline__ float rcpf(float x) {
    float r; asm("v_rcp_f32 %0, %1" : "=v"(r) : "v"(x)); return r;
}
__device__ __forceinline__ float sigm(float z) { return rcpf(1.0f + __expf(-z)); }
__device__ __forceinline__ float tanh_f(float z) {
    return fmaf(-2.0f, rcpf(__expf(2.0f * z) + 1.0f), 1.0f);  // inf-safe both ends
}
__device__ __forceinline__ bf16x8 cvt8(f32x4 a, f32x4 b) {
    bf16x8 r;
    r[0] = (__bf16)a[0]; r[1] = (__bf16)a[1]; r[2] = (__bf16)a[2]; r[3] = (__bf16)a[3];
    r[4] = (__bf16)b[0]; r[5] = (__bf16)b[1]; r[6] = (__bf16)b[2]; r[7] = (__bf16)b[3];
    return r;
}
__device__ __forceinline__ bf16x8 ld8(const float* p) {
    f32x4 a = *(const f32x4*)p;
    f32x4 b = *(const f32x4*)(p + 4);
    return cvt8(a, b);
}
__device__ __forceinline__ f32x4 mfma16(bf16x8 a, bf16x8 b, f32x4 c) {
    return __builtin_amdgcn_mfma_f32_16x16x32_bf16(a, b, c, 0, 0, 0);
}

// Relaxed barrier: order LDS (lgkmcnt) ONLY; global loads/stores stay in
// flight across the barrier (T4). sched_barrier(0) per rule #18.
__device__ __forceinline__ void lds_barrier() {
    asm volatile("s_waitcnt lgkmcnt(0)" ::: "memory");
    __builtin_amdgcn_s_barrier();
    __builtin_amdgcn_sched_barrier(0);
}

// 256 WGs x 4 batch rows, 8 waves, 1 block/CU. R14-verified skeleton (599us)
// + x-path rebalance (R16) with the RACE FIXED by 2-step skew + triple buffer:
//   consumer wave 4+cw, window t: computes gx(t+2) = b + x(t+2)*Wih0 (and
//   shortcut b + x*Ws0) for producer wave cw -> gxb slot (t+2)%3.
//   producer wave w, window t: reads gx(t) from slot t%3.
// Interval proof: write gx(k) in (B1(k-2),B1(k-1)); read in (B1(k-1),B1(k))
// -> ordered by B1(k-1). WAR: slot rewritten in (B1(k+1),B1(k+2)), after the
// read drained at B1(k). Bootstrap: gx(0)->slot0, gx(1)->slot1 pre-loop,
// fenced by __syncthreads. Accumulation order unchanged (a={b}; a=mfma(x,Wih,a);
// then 4 h-MFMAs) -> bit-identical numerics to R14.
__global__ __launch_bounds__(512, 2) void resid_lstm(
    const float* __restrict__ x,
    const float* __restrict__ h0i, const float* __restrict__ c0i,
    const float* __restrict__ h1i, const float* __restrict__ c1i,
    const float* __restrict__ Wih0, const float* __restrict__ Whh0,
    const float* __restrict__ bih0, const float* __restrict__ bhh0,
    const float* __restrict__ Ws0,  const float* __restrict__ bs0v,
    const float* __restrict__ Wih1, const float* __restrict__ Whh1,
    const float* __restrict__ bih1, const float* __restrict__ bhh1,
    const float* __restrict__ Ws1,  const float* __restrict__ bs1v,
    float* __restrict__ out)
{
    const int tid  = threadIdx.x;
    const int lane = tid & 63;
    const int w    = tid >> 6;        // wave 0..7
    const int fr   = lane & 15;       // A-row index within tile / C col (unit)
    const int fk   = lane >> 4;       // k-group; also this lane's batch row
    const int row0 = blockIdx.x * RPW;
    const bool prod = (w < 4);
    const int arow = fr >> 2;         // A-row batch index (rows duplicated x4)

    __shared__ __align__(16) float h0f[2][RPW][S0];   // h0 state (fp32)
    __shared__ __align__(16) float i1f[2][RPW][S0];   // clip(h0) (fp32)
    __shared__ __align__(16) float h1q[2][RPW][S1];   // h1 state (fp32)
    // x-path gate tiles: [slot][prod wave][slice*5+gate(4=shortcut)][lane*4]
    // contiguous 1KB per tile -> conflict-free b128 read/write. 120KB.
    __shared__ __align__(16) float gxb[3][4][10][256];

    // zero state LDS (gxb needs none: every read location written pre-read)
    for (int i = tid; i < 2 * RPW * S0; i += 512) {
        (&h0f[0][0][0])[i] = 0.f;
        (&i1f[0][0][0])[i] = 0.f;
    }
    for (int i = tid; i < 2 * RPW * S1; i += 512)
        (&h1q[0][0][0])[i] = 0.f;
    __syncthreads();

    bf16x8 WH[32];            // producer: Whh0 frags (2 slices x 4 gates x 4)
    bf16x8 W1[28], WX[10];    // consumer: layer1 frags + producer x-weights
    float BZ[5];              // consumer: layer1 folded biases
    float BX[10];             // consumer: layer0 x-path biases
    float CS[2];              // c-state: producer c0[sl]; consumer c1 in CS[0]
    CS[0] = 0.f; CS[1] = 0.f;

    if (prod) {
        #pragma unroll
        for (int sl = 0; sl < 2; ++sl) {
            const int u = (w + 4*sl)*16 + fr;
            #pragma unroll
            for (int g = 0; g < 4; ++g) {
                const int r0 = g*H0D + u;             // gate order i,f,g,o
                #pragma unroll
                for (int ks = 0; ks < 4; ++ks)
                    WH[sl*16 + g*4 + ks] = ld8(Whh0 + r0*H0D + ks*32 + fk*8);
            }
            CS[sl] = c0i[(size_t)(row0 + fk)*H0D + u];
        }
    } else {
        const int u1 = (w - 4)*16 + fr;
        #pragma unroll
        for (int g = 0; g < 4; ++g) {
            const int r1 = g*H1D + u1;
            #pragma unroll
            for (int ks = 0; ks < 4; ++ks)
                W1[g*6 + ks] = ld8(Wih1 + r1*H0D + ks*32 + fk*8);
            #pragma unroll
            for (int k2 = 0; k2 < 2; ++k2)
                W1[g*6 + 4 + k2] = ld8(Whh1 + r1*H1D + k2*32 + fk*8);
            BZ[g] = bih1[r1] + bhh1[r1];
        }
        #pragma unroll
        for (int ks = 0; ks < 4; ++ks)
            W1[24 + ks] = ld8(Ws1 + u1*H0D + ks*32 + fk*8);
        BZ[4] = bs1v[u1];
        CS[0] = c1i[(size_t)(row0 + fk)*H1D + u1];
        // x-path weights/biases for the producer wave this consumer serves
        const int cw = w - 4;
        #pragma unroll
        for (int sl = 0; sl < 2; ++sl) {
            const int u0 = (cw + 4*sl)*16 + fr;
            #pragma unroll
            for (int g = 0; g < 4; ++g) {
                const int r0 = g*H0D + u0;
                WX[sl*5 + g] = ld8(Wih0 + r0*IND + fk*8);
                BX[sl*5 + g] = bih0[r0] + bhh0[r0];
            }
            WX[sl*5 + 4] = ld8(Ws0 + u0*IND + fk*8);
            BX[sl*5 + 4] = bs0v[u0];
        }
    }

    // initial hidden states -> LDS fp32 (both read at t=0 from buffer 0)
    {
        const int u = tid & 127, b2 = tid >> 7;
        h0f[0][b2][u] = h0i[(size_t)(row0 + b2)*H0D + u];
    }
    if (tid < RPW * H1D) {
        const int u = tid & 63, b2 = tid >> 6;
        h1q[0][b2][u] = h1i[(size_t)(row0 + b2)*H1D + u];
    }

    const float* xbase = x + ((size_t)row0 + arow)*IND + fk*8;
    f32x4 xa = {0,0,0,0}, xb = {0,0,0,0};
    if (!prod) {
        const int cw = w - 4;
        // bootstrap: gx(0) -> slot 0, gx(1) -> slot 1 (fenced by syncthreads)
        #pragma unroll
        for (int t0 = 0; t0 < 2; ++t0) {
            const float* xp = xbase + (size_t)t0 * (BB*IND);
            f32x4 x0a = *(const f32x4*)xp;
            f32x4 x0b = *(const f32x4*)(xp + 4);
            bf16x8 xf0 = cvt8(x0a, x0b);
            #pragma unroll
            for (int i = 0; i < 10; ++i) {
                const float b = BX[i];
                f32x4 a = {b, b, b, b};
                a = mfma16(xf0, WX[i], a);
                *(f32x4*)&gxb[t0][cw][i][lane*4] = a;
            }
        }
        // prefetch x(2) (consumed at window 0 as the gx(2) input)
        const float* xp = xbase + (size_t)2 * (BB*IND);
        xa = *(const f32x4*)xp; xb = *(const f32x4*)(xp + 4);
    }

    __syncthreads();

    const size_t H0O = (size_t)TS*BB*H1D;
    const size_t C0O = H0O + (size_t)BB*H0D;
    const size_t H1O = C0O + (size_t)BB*H0D;
    const size_t C1O = H1O + (size_t)BB*H1D;

    int st = 0;   // slot holding gx(t); write slot = (t+2)%3 = (st+2)%3

    #pragma unroll 1
    for (int t = 0; t < TS; ++t) {
        const int rp = t & 1;
        // ========== Phase 1: layer0, step t (waves 0-3) ==========
        if (prod) {
            bf16x8 hf[4];
            #pragma unroll
            for (int ks = 0; ks < 4; ++ks)
                hf[ks] = ld8(&h0f[rp][arow][ks*32 + fk*8]);

            #pragma unroll
            for (int sl = 0; sl < 2; ++sl) {
                const int u = (w + 4*sl)*16 + fr;
                f32x4 ag[5];
                #pragma unroll
                for (int g = 0; g < 4; ++g) {
                    // C-init = staged (b + x*Wih) tile -> only 4 h-MFMAs
                    f32x4 a = *(const f32x4*)&gxb[st][w][sl*5 + g][lane*4];
                    #pragma unroll
                    for (int ks = 0; ks < 4; ++ks)
                        a = mfma16(hf[ks], WH[sl*16 + g*4 + ks], a);
                    ag[g] = a;
                }
                ag[4] = *(const f32x4*)&gxb[st][w][sl*5 + 4][lane*4]; // shortcut

                // lane's element: batch row fk (C row 4*fk -> reg 0), unit u
                const float i_ = sigm(ag[0][0]);
                const float f_ = sigm(ag[1][0]);
                const float g_ = tanh_f(ag[2][0]);
                const float o_ = sigm(ag[3][0]);
                const float c  = fmaf(f_, CS[sl], i_ * g_);
                CS[sl] = c;
                const float hn = fmaf(o_, tanh_f(c), ag[4][0]);   // pre-clip state
                const float iv = fminf(fmaxf(hn, -10.f), 10.f);   // layer1 input
                h0f[rp ^ 1][fk][u] = hn;     // fp32 dword: one writer lane each
                i1f[rp ^ 1][fk][u] = iv;
                if (t == TS - 1) {
                    out[H0O + (size_t)(row0 + fk)*H0D + u] = hn;
                    out[C0O + (size_t)(row0 + fk)*H0D + u] = c;
                }
            }
        }
        lds_barrier();   // B1: LDS-ordered only; vmem stays in flight

        // ========== Phase 2: consumers (waves 4-7) ==========
        if (!prod) {
            const int cw = w - 4;
            // --- stage gx(t+2) -> slot (t+2)%3 (2-step skew: fenced by
            //     B1(t+1) before the producer's read at window t+2) ---
            const int sw = (st + 2 >= 3) ? st - 1 : st + 2;
            bf16x8 xf = cvt8(xa, xb);   // x(t+2)
            {   // prefetch x(t+3); stays in flight across barriers
                const int tn = (t + 3 < TS) ? (t + 3) : TS - 1;
                const float* xp = xbase + (size_t)tn * (BB*IND);
                xa = *(const f32x4*)xp; xb = *(const f32x4*)(xp + 4);
            }
            #pragma unroll
            for (int i = 0; i < 10; ++i) {
                const float b = BX[i];
                f32x4 a = {b, b, b, b};
                a = mfma16(xf, WX[i], a);
                *(f32x4*)&gxb[sw][cw][i][lane*4] = a;
            }

            // --- layer1, step t (unchanged from R14) ---
            bf16x8 pf[4], hq[2];
            #pragma unroll
            for (int ks = 0; ks < 4; ++ks)
                pf[ks] = ld8(&i1f[rp ^ 1][arow][ks*32 + fk*8]);
            #pragma unroll
            for (int k2 = 0; k2 < 2; ++k2)
                hq[k2] = ld8(&h1q[rp][arow][k2*32 + fk*8]);

            const int u1 = cw*16 + fr;
            f32x4 a1[5];
            #pragma unroll
            for (int g = 0; g < 4; ++g) {
                const float b = BZ[g];
                f32x4 a = {b, b, b, b};
                #pragma unroll
                for (int ks = 0; ks < 4; ++ks)
                    a = mfma16(pf[ks], W1[g*6 + ks], a);
                #pragma unroll
                for (int k2 = 0; k2 < 2; ++k2)
                    a = mfma16(hq[k2], W1[g*6 + 4 + k2], a);
                a1[g] = a;
            }
            {
                const float b = BZ[4];
                f32x4 a = {b, b, b, b};
                #pragma unroll
                for (int ks = 0; ks < 4; ++ks)
                    a = mfma16(pf[ks], W1[24 + ks], a);
                a1[4] = a;
            }
            const float i_ = sigm(a1[0][0]);
            const float f_ = sigm(a1[1][0]);
            const float g_ = tanh_f(a1[2][0]);
            const float o_ = sigm(a1[3][0]);
            const float c  = fmaf(f_, CS[0], i_ * g_);
            CS[0] = c;
            const float hn = fmaf(o_, tanh_f(c), a1[4][0]);   // pre-clip state
            const float yv = fminf(fmaxf(hn, -10.f), 10.f);
            out[((size_t)t*BB + row0 + fk)*H1D + u1] = yv;   // store in flight
            h1q[rp ^ 1][fk][u1] = hn;
            if (t == TS - 1) {
                out[H1O + (size_t)(row0 + fk)*H1D + u1] = hn;
                out[C1O + (size_t)(row0 + fk)*H1D + u1] = c;
            }
        }
        st = (st + 1 >= 3) ? 0 : st + 1;
        // no trailing barrier: producer(t+1) writes buffers disjoint from
        // consumer(t) reads; gx slot reuse fenced per the interval proof above.
    }
}

} // namespace

extern "C" void kernel_launch(void* const* d_in, const int* in_sizes, int n_in,
                              void* d_out, int out_size, void* d_ws, size_t ws_size,
                              hipStream_t stream) {
    (void)in_sizes; (void)n_in; (void)d_ws; (void)ws_size; (void)out_size;
    const float* x    = (const float*)d_in[0];
    const float* h0i  = (const float*)d_in[1];
    const float* c0i  = (const float*)d_in[2];
    const float* h1i  = (const float*)d_in[3];
    const float* c1i  = (const float*)d_in[4];
    const float* Wih0 = (const float*)d_in[5];
    const float* Whh0 = (const float*)d_in[6];
    const float* bih0 = (const float*)d_in[7];
    const float* bhh0 = (const float*)d_in[8];
    const float* Ws0  = (const float*)d_in[9];
    const float* bs0  = (const float*)d_in[10];
    const float* Wih1 = (const float*)d_in[11];
    const float* Whh1 = (const float*)d_in[12];
    const float* bih1 = (const float*)d_in[13];
    const float* bhh1 = (const float*)d_in[14];
    const float* Ws1  = (const float*)d_in[15];
    const float* bs1  = (const float*)d_in[16];

    resid_lstm<<<dim3(BB / RPW), dim3(512), 0, stream>>>(
        x, h0i, c0i, h1i, c1i,
        Wih0, Whh0, bih0, bhh0, Ws0, bs0,
        Wih1, Whh1, bih1, bhh1, Ws1, bs1,
        (float*)d_out);
}

// Round 18
// 4365.961 us; speedup vs baseline: 1.1325x; 1.1325x over previous
//
#include <hip/hip_runtime.h>
#include <cstdint>
#include <cstddef>

namespace {

constexpr int TS  = 512;   // timesteps
constexpr int BB  = 1024;  // batch
constexpr int IND = 32;    // input dim
constexpr int H0D = 128;   // layer0 hidden
constexpr int H1D = 64;    // layer1 hidden
constexpr int RPW = 4;     // batch rows per WG -> 256 WGs = 1 block/CU
constexpr int S0  = 132;   // padded LDS row stride (floats) for 128-wide state
constexpr int S1  = 68;    // padded LDS row stride (floats) for 64-wide state

typedef float f32x4 __attribute__((ext_vector_type(4)));
typedef __bf16 bf16x8 __attribute__((ext_vector_type(8)));

__device__ __forceinline__ float rcpf(float x) {
    float r; asm("v_rcp_f32 %0, %1" : "=v"(r) : "v"(x)); return r;
}
__device__ __forceinline__ float sigm(float z) { return rcpf(1.0f + __expf(-z)); }
__device__ __forceinline__ float tanh_f(float z) {
    return fmaf(-2.0f, rcpf(__expf(2.0f * z) + 1.0f), 1.0f);  // inf-safe both ends
}
__device__ __forceinline__ bf16x8 cvt8(f32x4 a, f32x4 b) {
    bf16x8 r;
    r[0] = (__bf16)a[0]; r[1] = (__bf16)a[1]; r[2] = (__bf16)a[2]; r[3] = (__bf16)a[3];
    r[4] = (__bf16)b[0]; r[5] = (__bf16)b[1]; r[6] = (__bf16)b[2]; r[7] = (__bf16)b[3];
    return r;
}
__device__ __forceinline__ bf16x8 ld8(const float* p) {
    f32x4 a = *(const f32x4*)p;
    f32x4 b = *(const f32x4*)(p + 4);
    return cvt8(a, b);
}
__device__ __forceinline__ f32x4 mfma16(bf16x8 a, bf16x8 b, f32x4 c) {
    return __builtin_amdgcn_mfma_f32_16x16x32_bf16(a, b, c, 0, 0, 0);
}

// Relaxed barrier: order LDS (lgkmcnt) ONLY; global loads/stores stay in
// flight across the barrier (T4). sched_barrier(0) per rule #18.
__device__ __forceinline__ void lds_barrier() {
    asm volatile("s_waitcnt lgkmcnt(0)" ::: "memory");
    __builtin_amdgcn_s_barrier();
    __builtin_amdgcn_sched_barrier(0);
}

// 256 WGs x 4 batch rows, 8 waves, 1 block/CU. R14 skeleton (599us) +
// x-path rebalance with REGISTER DISCIPLINE (R17 spilled at 38 frags/wave;
// cliff is between 33 and 38 — split staging across ALL 8 waves):
//   producer wave w:   WH[32] + WX[5] (slice 0 x-weights)   = 37 frags
//   consumer wave 4+cw: W1[28] + WX[5] (slice 1 x-weights)  = 33 frags
// gx(t+2) staged into gxb slot (t+2)%3: producer writes its slice-0 tiles
// in (B1(t-1),B1(t)); consumer writes slice-1 tiles in (B1(t),B1(t+1));
// producer reads slot t%3 in (B1(t-1),B1(t)) — >=1 barrier after both
// writers; WAR separations >=1 barrier (t%3 cycle). Bootstrap gx(0),gx(1)
// pre-loop, fenced by __syncthreads. Accumulation order unchanged
// (a={b}; a=mfma(x,Wih,a); then 4 h-MFMAs) -> bit-identical numerics.
__global__ __launch_bounds__(512, 2) void resid_lstm(
    const float* __restrict__ x,
    const float* __restrict__ h0i, const float* __restrict__ c0i,
    const float* __restrict__ h1i, const float* __restrict__ c1i,
    const float* __restrict__ Wih0, const float* __restrict__ Whh0,
    const float* __restrict__ bih0, const float* __restrict__ bhh0,
    const float* __restrict__ Ws0,  const float* __restrict__ bs0v,
    const float* __restrict__ Wih1, const float* __restrict__ Whh1,
    const float* __restrict__ bih1, const float* __restrict__ bhh1,
    const float* __restrict__ Ws1,  const float* __restrict__ bs1v,
    float* __restrict__ out)
{
    const int tid  = threadIdx.x;
    const int lane = tid & 63;
    const int w    = tid >> 6;        // wave 0..7
    const int fr   = lane & 15;       // A-row index within tile / C col (unit)
    const int fk   = lane >> 4;       // k-group; also this lane's batch row
    const int row0 = blockIdx.x * RPW;
    const bool prod = (w < 4);
    const int arow = fr >> 2;         // A-row batch index (rows duplicated x4)

    __shared__ __align__(16) float h0f[2][RPW][S0];   // h0 state (fp32)
    __shared__ __align__(16) float i1f[2][RPW][S0];   // clip(h0) (fp32)
    __shared__ __align__(16) float h1q[2][RPW][S1];   // h1 state (fp32)
    // x-path gate tiles: [slot][prod wave][slice*5+gate(4=shortcut)][lane*4]
    __shared__ __align__(16) float gxb[3][4][10][256];   // 120 KB

    // zero state LDS (gxb: every read location written pre-read)
    for (int i = tid; i < 2 * RPW * S0; i += 512) {
        (&h0f[0][0][0])[i] = 0.f;
        (&i1f[0][0][0])[i] = 0.f;
    }
    for (int i = tid; i < 2 * RPW * S1; i += 512)
        (&h1q[0][0][0])[i] = 0.f;
    __syncthreads();

    bf16x8 WH[32];    // producer: Whh0 frags (2 slices x 4 gates x 4)
    bf16x8 W1[28];    // consumer: layer1 frags
    bf16x8 WX[5];     // BOTH: x-path weights for ONE slice (4 gates + ws0)
    float  BX[5];     // x-path biases for that slice
    float  BZ[5];     // consumer: layer1 folded biases
    float  CS[2];     // c-state: producer c0[sl]; consumer c1 in CS[0]
    CS[0] = 0.f; CS[1] = 0.f;

    // xsl: which slice's x-tiles this wave stages; xw: for which producer wave
    const int xw  = prod ? w : (w - 4);
    const int xsl = prod ? 0 : 1;
    {
        const int u0 = (xw + 4*xsl)*16 + fr;
        #pragma unroll
        for (int g = 0; g < 4; ++g) {
            const int r0 = g*H0D + u0;
            WX[g] = ld8(Wih0 + r0*IND + fk*8);
            BX[g] = bih0[r0] + bhh0[r0];
        }
        WX[4] = ld8(Ws0 + u0*IND + fk*8);
        BX[4] = bs0v[u0];
    }

    if (prod) {
        #pragma unroll
        for (int sl = 0; sl < 2; ++sl) {
            const int u = (w + 4*sl)*16 + fr;
            #pragma unroll
            for (int g = 0; g < 4; ++g) {
                const int r0 = g*H0D + u;             // gate order i,f,g,o
                #pragma unroll
                for (int ks = 0; ks < 4; ++ks)
                    WH[sl*16 + g*4 + ks] = ld8(Whh0 + r0*H0D + ks*32 + fk*8);
            }
            CS[sl] = c0i[(size_t)(row0 + fk)*H0D + u];
        }
    } else {
        const int u1 = (w - 4)*16 + fr;
        #pragma unroll
        for (int g = 0; g < 4; ++g) {
            const int r1 = g*H1D + u1;
            #pragma unroll
            for (int ks = 0; ks < 4; ++ks)
                W1[g*6 + ks] = ld8(Wih1 + r1*H0D + ks*32 + fk*8);
            #pragma unroll
            for (int k2 = 0; k2 < 2; ++k2)
                W1[g*6 + 4 + k2] = ld8(Whh1 + r1*H1D + k2*32 + fk*8);
            BZ[g] = bih1[r1] + bhh1[r1];
        }
        #pragma unroll
        for (int ks = 0; ks < 4; ++ks)
            W1[24 + ks] = ld8(Ws1 + u1*H0D + ks*32 + fk*8);
        BZ[4] = bs1v[u1];
        CS[0] = c1i[(size_t)(row0 + fk)*H1D + u1];
    }

    // initial hidden states -> LDS fp32 (both read at t=0 from buffer 0)
    {
        const int u = tid & 127, b2 = tid >> 7;
        h0f[0][b2][u] = h0i[(size_t)(row0 + b2)*H0D + u];
    }
    if (tid < RPW * H1D) {
        const int u = tid & 63, b2 = tid >> 6;
        h1q[0][b2][u] = h1i[(size_t)(row0 + b2)*H1D + u];
    }

    const float* xbase = x + ((size_t)row0 + arow)*IND + fk*8;
    // bootstrap: every wave stages its slice of gx(0)->slot0, gx(1)->slot1
    #pragma unroll
    for (int t0 = 0; t0 < 2; ++t0) {
        const float* xp = xbase + (size_t)t0 * (BB*IND);
        f32x4 x0a = *(const f32x4*)xp;
        f32x4 x0b = *(const f32x4*)(xp + 4);
        bf16x8 xf0 = cvt8(x0a, x0b);
        #pragma unroll
        for (int i = 0; i < 5; ++i) {
            const float b = BX[i];
            f32x4 a = {b, b, b, b};
            a = mfma16(xf0, WX[i], a);
            *(f32x4*)&gxb[t0][xw][xsl*5 + i][lane*4] = a;
        }
    }
    // prefetch x(2) (consumed at window 0 as the gx(2) input)
    f32x4 xa, xb;
    {
        const float* xp = xbase + (size_t)2 * (BB*IND);
        xa = *(const f32x4*)xp; xb = *(const f32x4*)(xp + 4);
    }

    __syncthreads();

    const size_t H0O = (size_t)TS*BB*H1D;
    const size_t C0O = H0O + (size_t)BB*H0D;
    const size_t H1O = C0O + (size_t)BB*H0D;
    const size_t C1O = H1O + (size_t)BB*H1D;

    int st = 0;   // slot holding gx(t); write slot sw = (t+2)%3

    #pragma unroll 1
    for (int t = 0; t < TS; ++t) {
        const int rp = t & 1;
        const int sw = (st + 2 >= 3) ? st - 1 : st + 2;
        // x(t+2) fragment + prefetch x(t+3) (both roles stage gx)
        bf16x8 xf = cvt8(xa, xb);
        {
            const int tn = (t + 3 < TS) ? (t + 3) : TS - 1;
            const float* xp = xbase + (size_t)tn * (BB*IND);
            xa = *(const f32x4*)xp; xb = *(const f32x4*)(xp + 4);
        }

        // ========== Phase 1: layer0, step t (waves 0-3) ==========
        if (prod) {
            bf16x8 hf[4];
            #pragma unroll
            for (int ks = 0; ks < 4; ++ks)
                hf[ks] = ld8(&h0f[rp][arow][ks*32 + fk*8]);

            #pragma unroll
            for (int sl = 0; sl < 2; ++sl) {
                const int u = (w + 4*sl)*16 + fr;
                f32x4 ag[5];
                #pragma unroll
                for (int g = 0; g < 4; ++g) {
                    // C-init = staged (b + x*Wih) tile -> only 4 h-MFMAs
                    f32x4 a = *(const f32x4*)&gxb[st][w][sl*5 + g][lane*4];
                    #pragma unroll
                    for (int ks = 0; ks < 4; ++ks)
                        a = mfma16(hf[ks], WH[sl*16 + g*4 + ks], a);
                    ag[g] = a;
                }
                ag[4] = *(const f32x4*)&gxb[st][w][sl*5 + 4][lane*4]; // shortcut

                const float i_ = sigm(ag[0][0]);
                const float f_ = sigm(ag[1][0]);
                const float g_ = tanh_f(ag[2][0]);
                const float o_ = sigm(ag[3][0]);
                const float c  = fmaf(f_, CS[sl], i_ * g_);
                CS[sl] = c;
                const float hn = fmaf(o_, tanh_f(c), ag[4][0]);   // pre-clip state
                const float iv = fminf(fmaxf(hn, -10.f), 10.f);   // layer1 input
                h0f[rp ^ 1][fk][u] = hn;     // fp32 dword: one writer lane each
                i1f[rp ^ 1][fk][u] = iv;
                if (t == TS - 1) {
                    out[H0O + (size_t)(row0 + fk)*H0D + u] = hn;
                    out[C0O + (size_t)(row0 + fk)*H0D + u] = c;
                }
            }
            // stage gx(t+2) slice 0 (independent x-MFMAs; fill dep stalls)
            #pragma unroll
            for (int i = 0; i < 5; ++i) {
                const float b = BX[i];
                f32x4 a = {b, b, b, b};
                a = mfma16(xf, WX[i], a);
                *(f32x4*)&gxb[sw][w][i][lane*4] = a;
            }
        }
        lds_barrier();   // B1: LDS-ordered only; vmem stays in flight

        // ========== Phase 2: consumers (waves 4-7) ==========
        if (!prod) {
            const int cw = w - 4;
            // stage gx(t+2) slice 1 for producer wave cw
            #pragma unroll
            for (int i = 0; i < 5; ++i) {
                const float b = BX[i];
                f32x4 a = {b, b, b, b};
                a = mfma16(xf, WX[i], a);
                *(f32x4*)&gxb[sw][cw][5 + i][lane*4] = a;
            }

            // layer1, step t (unchanged from R14)
            bf16x8 pf[4], hq[2];
            #pragma unroll
            for (int ks = 0; ks < 4; ++ks)
                pf[ks] = ld8(&i1f[rp ^ 1][arow][ks*32 + fk*8]);
            #pragma unroll
            for (int k2 = 0; k2 < 2; ++k2)
                hq[k2] = ld8(&h1q[rp][arow][k2*32 + fk*8]);

            const int u1 = cw*16 + fr;
            f32x4 a1[5];
            #pragma unroll
            for (int g = 0; g < 4; ++g) {
                const float b = BZ[g];
                f32x4 a = {b, b, b, b};
                #pragma unroll
                for (int ks = 0; ks < 4; ++ks)
                    a = mfma16(pf[ks], W1[g*6 + ks], a);
                #pragma unroll
                for (int k2 = 0; k2 < 2; ++k2)
                    a = mfma16(hq[k2], W1[g*6 + 4 + k2], a);
                a1[g] = a;
            }
            {
                const float b = BZ[4];
                f32x4 a = {b, b, b, b};
                #pragma unroll
                for (int ks = 0; ks < 4; ++ks)
                    a = mfma16(pf[ks], W1[24 + ks], a);
                a1[4] = a;
            }
            const float i_ = sigm(a1[0][0]);
            const float f_ = sigm(a1[1][0]);
            const float g_ = tanh_f(a1[2][0]);
            const float o_ = sigm(a1[3][0]);
            const float c  = fmaf(f_, CS[0], i_ * g_);
            CS[0] = c;
            const float hn = fmaf(o_, tanh_f(c), a1[4][0]);   // pre-clip state
            const float yv = fminf(fmaxf(hn, -10.f), 10.f);
            out[((size_t)t*BB + row0 + fk)*H1D + u1] = yv;   // store in flight
            h1q[rp ^ 1][fk][u1] = hn;
            if (t == TS - 1) {
                out[H1O + (size_t)(row0 + fk)*H1D + u1] = hn;
                out[C1O + (size_t)(row0 + fk)*H1D + u1] = c;
            }
        }
        st = (st + 1 >= 3) ? 0 : st + 1;
        // no trailing barrier: producer(t+1) writes buffers disjoint from
        // consumer(t) reads; gx slot handoffs fenced per the interval proof.
    }
}

} // namespace

extern "C" void kernel_launch(void* const* d_in, const int* in_sizes, int n_in,
                              void* d_out, int out_size, void* d_ws, size_t ws_size,
                              hipStream_t stream) {
    (void)in_sizes; (void)n_in; (void)d_ws; (void)ws_size; (void)out_size;
    const float* x    = (const float*)d_in[0];
    const float* h0i  = (const float*)d_in[1];
    const float* c0i  = (const float*)d_in[2];
    const float* h1i  = (const float*)d_in[3];
    const float* c1i  = (const float*)d_in[4];
    const float* Wih0 = (const float*)d_in[5];
    const float* Whh0 = (const float*)d_in[6];
    const float* bih0 = (const float*)d_in[7];
    const float* bhh0 = (const float*)d_in[8];
    const float* Ws0  = (const float*)d_in[9];
    const float* bs0  = (const float*)d_in[10];
    const float* Wih1 = (const float*)d_in[11];
    const float* Whh1 = (const float*)d_in[12];
    const float* bih1 = (const float*)d_in[13];
    const float* bhh1 = (const float*)d_in[14];
    const float* Ws1  = (const float*)d_in[15];
    const float* bs1  = (const float*)d_in[16];

    resid_lstm<<<dim3(BB / RPW), dim3(512), 0, stream>>>(
        x, h0i, c0i, h1i, c1i,
        Wih0, Whh0, bih0, bhh0, Ws0, bs0,
        Wih1, Whh1, bih1, bhh1, Ws1, bs1,
        (float*)d_out);
}

// Round 19
// 612.118 us; speedup vs baseline: 8.0777x; 7.1326x over previous
//
#include <hip/hip_runtime.h>
#include <cstdint>
#include <cstddef>

namespace {

constexpr int TS  = 512;   // timesteps
constexpr int BB  = 1024;  // batch
constexpr int IND = 32;    // input dim
constexpr int H0D = 128;   // layer0 hidden
constexpr int H1D = 64;    // layer1 hidden
constexpr int RPW = 4;     // batch rows per WG -> 256 WGs = 1 block/CU
constexpr int S0  = 132;   // padded LDS row stride (floats) for 128-wide state
constexpr int S1  = 68;    // padded LDS row stride (floats) for 64-wide state

typedef float f32x4 __attribute__((ext_vector_type(4)));
typedef __bf16 bf16x8 __attribute__((ext_vector_type(8)));

__device__ __forceinline__ float rcpf(float x) {
    float r; asm("v_rcp_f32 %0, %1" : "=v"(r) : "v"(x)); return r;
}
__device__ __forceinline__ float sigm(float z) { return rcpf(1.0f + __expf(-z)); }
__device__ __forceinline__ float tanh_f(float z) {
    return fmaf(-2.0f, rcpf(__expf(2.0f * z) + 1.0f), 1.0f);  // inf-safe both ends
}
__device__ __forceinline__ bf16x8 cvt8(f32x4 a, f32x4 b) {
    bf16x8 r;
    r[0] = (__bf16)a[0]; r[1] = (__bf16)a[1]; r[2] = (__bf16)a[2]; r[3] = (__bf16)a[3];
    r[4] = (__bf16)b[0]; r[5] = (__bf16)b[1]; r[6] = (__bf16)b[2]; r[7] = (__bf16)b[3];
    return r;
}
__device__ __forceinline__ bf16x8 ld8(const float* p) {
    f32x4 a = *(const f32x4*)p;
    f32x4 b = *(const f32x4*)(p + 4);
    return cvt8(a, b);
}
__device__ __forceinline__ f32x4 mfma16(bf16x8 a, bf16x8 b, f32x4 c) {
    return __builtin_amdgcn_mfma_f32_16x16x32_bf16(a, b, c, 0, 0, 0);
}

// Relaxed barrier: order LDS (lgkmcnt) ONLY; global loads/stores stay in
// flight across the barrier (T4). sched_barrier(0) per rule #18.
__device__ __forceinline__ void lds_barrier() {
    asm volatile("s_waitcnt lgkmcnt(0)" ::: "memory");
    __builtin_amdgcn_s_barrier();
    __builtin_amdgcn_sched_barrier(0);
}

// 256 WGs x 4 batch rows, 8 waves, 1 block/CU. R14 skeleton + x-path
// rebalance (R16 concept, R17 fence fix). REGISTER FIX vs R18: both roles'
// weights live in ONE WF[37] array so the allocator overlays storage
// (R9's working pattern). Separate conditionally-initialized arrays forced
// the union (~65 frags ~260 VGPR) -> scratch spill (R17/R18 FETCH 10/1.6 GB).
//   producer wave w:   WF[0..31]=Whh0 (2 slices x 4 gates x 4), WF[32..36]=
//                      slice-0 x-weights (4 gates + ws0)        = 37 frags
//   consumer wave 4+cw: WF[0..27]=layer1, WF[32..36]=slice-1 x-wts = 33 frags
// gx(t+2) staged into gxb slot (t+2)%3: producer writes slice-0 tiles in
// (B1(t-1),B1(t)); consumer writes slice-1 in (B1(t),B1(t+1)); producer
// reads slot t%3 in (B1(t-1),B1(t)) — >=1 barrier after both writers; WAR
// separations >=1 barrier. Bootstrap gx(0),gx(1) pre-loop (syncthreads).
// Accumulation order unchanged -> bit-identical numerics (absmax 0.015625).
__global__ __launch_bounds__(512, 2) void resid_lstm(
    const float* __restrict__ x,
    const float* __restrict__ h0i, const float* __restrict__ c0i,
    const float* __restrict__ h1i, const float* __restrict__ c1i,
    const float* __restrict__ Wih0, const float* __restrict__ Whh0,
    const float* __restrict__ bih0, const float* __restrict__ bhh0,
    const float* __restrict__ Ws0,  const float* __restrict__ bs0v,
    const float* __restrict__ Wih1, const float* __restrict__ Whh1,
    const float* __restrict__ bih1, const float* __restrict__ bhh1,
    const float* __restrict__ Ws1,  const float* __restrict__ bs1v,
    float* __restrict__ out)
{
    const int tid  = threadIdx.x;
    const int lane = tid & 63;
    const int w    = tid >> 6;        // wave 0..7
    const int fr   = lane & 15;       // A-row index within tile / C col (unit)
    const int fk   = lane >> 4;       // k-group; also this lane's batch row
    const int row0 = blockIdx.x * RPW;
    const bool prod = (w < 4);
    const int arow = fr >> 2;         // A-row batch index (rows duplicated x4)

    __shared__ __align__(16) float h0f[2][RPW][S0];   // h0 state (fp32)
    __shared__ __align__(16) float i1f[2][RPW][S0];   // clip(h0) (fp32)
    __shared__ __align__(16) float h1q[2][RPW][S1];   // h1 state (fp32)
    // x-path gate tiles: [slot][prod wave][slice*5+gate(4=shortcut)][lane*4]
    __shared__ __align__(16) float gxb[3][4][10][256];   // 120 KB

    // zero state LDS (gxb: every read location written pre-read)
    for (int i = tid; i < 2 * RPW * S0; i += 512) {
        (&h0f[0][0][0])[i] = 0.f;
        (&i1f[0][0][0])[i] = 0.f;
    }
    for (int i = tid; i < 2 * RPW * S1; i += 512)
        (&h1q[0][0][0])[i] = 0.f;
    __syncthreads();

    bf16x8 WF[37];    // UNIONED weight file (see header comment)
    float  BX[5];     // x-path biases for this wave's staged slice
    float  BZ[5];     // consumer: layer1 folded biases
    float  CS[2];     // c-state: producer c0[sl]; consumer c1 in CS[0]
    CS[0] = 0.f; CS[1] = 0.f;

    // xsl: which slice's x-tiles this wave stages; xw: for which producer wave
    const int xw  = prod ? w : (w - 4);
    const int xsl = prod ? 0 : 1;
    {
        const int u0 = (xw + 4*xsl)*16 + fr;
        #pragma unroll
        for (int g = 0; g < 4; ++g) {
            const int r0 = g*H0D + u0;
            WF[32 + g] = ld8(Wih0 + r0*IND + fk*8);
            BX[g] = bih0[r0] + bhh0[r0];
        }
        WF[36] = ld8(Ws0 + u0*IND + fk*8);
        BX[4] = bs0v[u0];
    }

    if (prod) {
        #pragma unroll
        for (int sl = 0; sl < 2; ++sl) {
            const int u = (w + 4*sl)*16 + fr;
            #pragma unroll
            for (int g = 0; g < 4; ++g) {
                const int r0 = g*H0D + u;             // gate order i,f,g,o
                #pragma unroll
                for (int ks = 0; ks < 4; ++ks)
                    WF[sl*16 + g*4 + ks] = ld8(Whh0 + r0*H0D + ks*32 + fk*8);
            }
            CS[sl] = c0i[(size_t)(row0 + fk)*H0D + u];
        }
    } else {
        const int u1 = (w - 4)*16 + fr;
        #pragma unroll
        for (int g = 0; g < 4; ++g) {
            const int r1 = g*H1D + u1;
            #pragma unroll
            for (int ks = 0; ks < 4; ++ks)
                WF[g*6 + ks] = ld8(Wih1 + r1*H0D + ks*32 + fk*8);
            #pragma unroll
            for (int k2 = 0; k2 < 2; ++k2)
                WF[g*6 + 4 + k2] = ld8(Whh1 + r1*H1D + k2*32 + fk*8);
            BZ[g] = bih1[r1] + bhh1[r1];
        }
        #pragma unroll
        for (int ks = 0; ks < 4; ++ks)
            WF[24 + ks] = ld8(Ws1 + u1*H0D + ks*32 + fk*8);
        BZ[4] = bs1v[u1];
        CS[0] = c1i[(size_t)(row0 + fk)*H1D + u1];
    }

    // initial hidden states -> LDS fp32 (both read at t=0 from buffer 0)
    {
        const int u = tid & 127, b2 = tid >> 7;
        h0f[0][b2][u] = h0i[(size_t)(row0 + b2)*H0D + u];
    }
    if (tid < RPW * H1D) {
        const int u = tid & 63, b2 = tid >> 6;
        h1q[0][b2][u] = h1i[(size_t)(row0 + b2)*H1D + u];
    }

    const float* xbase = x + ((size_t)row0 + arow)*IND + fk*8;
    // bootstrap: every wave stages its slice of gx(0)->slot0, gx(1)->slot1
    #pragma unroll
    for (int t0 = 0; t0 < 2; ++t0) {
        const float* xp = xbase + (size_t)t0 * (BB*IND);
        f32x4 x0a = *(const f32x4*)xp;
        f32x4 x0b = *(const f32x4*)(xp + 4);
        bf16x8 xf0 = cvt8(x0a, x0b);
        #pragma unroll
        for (int i = 0; i < 5; ++i) {
            const float b = BX[i];
            f32x4 a = {b, b, b, b};
            a = mfma16(xf0, WF[32 + i], a);
            *(f32x4*)&gxb[t0][xw][xsl*5 + i][lane*4] = a;
        }
    }
    // prefetch x(2) (consumed at window 0 as the gx(2) input)
    f32x4 xa, xb;
    {
        const float* xp = xbase + (size_t)2 * (BB*IND);
        xa = *(const f32x4*)xp; xb = *(const f32x4*)(xp + 4);
    }

    __syncthreads();

    const size_t H0O = (size_t)TS*BB*H1D;
    const size_t C0O = H0O + (size_t)BB*H0D;
    const size_t H1O = C0O + (size_t)BB*H0D;
    const size_t C1O = H1O + (size_t)BB*H1D;

    int st = 0;   // slot holding gx(t); write slot sw = (t+2)%3

    #pragma unroll 1
    for (int t = 0; t < TS; ++t) {
        const int rp = t & 1;
        const int sw = (st + 2 >= 3) ? st - 1 : st + 2;
        // x(t+2) fragment + prefetch x(t+3) (both roles stage gx)
        bf16x8 xf = cvt8(xa, xb);
        {
            const int tn = (t + 3 < TS) ? (t + 3) : TS - 1;
            const float* xp = xbase + (size_t)tn * (BB*IND);
            xa = *(const f32x4*)xp; xb = *(const f32x4*)(xp + 4);
        }

        // ========== Phase 1: layer0, step t (waves 0-3) ==========
        if (prod) {
            bf16x8 hf[4];
            #pragma unroll
            for (int ks = 0; ks < 4; ++ks)
                hf[ks] = ld8(&h0f[rp][arow][ks*32 + fk*8]);

            #pragma unroll
            for (int sl = 0; sl < 2; ++sl) {
                const int u = (w + 4*sl)*16 + fr;
                f32x4 ag[5];
                #pragma unroll
                for (int g = 0; g < 4; ++g) {
                    // C-init = staged (b + x*Wih) tile -> only 4 h-MFMAs
                    f32x4 a = *(const f32x4*)&gxb[st][w][sl*5 + g][lane*4];
                    #pragma unroll
                    for (int ks = 0; ks < 4; ++ks)
                        a = mfma16(hf[ks], WF[sl*16 + g*4 + ks], a);
                    ag[g] = a;
                }
                ag[4] = *(const f32x4*)&gxb[st][w][sl*5 + 4][lane*4]; // shortcut

                const float i_ = sigm(ag[0][0]);
                const float f_ = sigm(ag[1][0]);
                const float g_ = tanh_f(ag[2][0]);
                const float o_ = sigm(ag[3][0]);
                const float c  = fmaf(f_, CS[sl], i_ * g_);
                CS[sl] = c;
                const float hn = fmaf(o_, tanh_f(c), ag[4][0]);   // pre-clip state
                const float iv = fminf(fmaxf(hn, -10.f), 10.f);   // layer1 input
                h0f[rp ^ 1][fk][u] = hn;     // fp32 dword: one writer lane each
                i1f[rp ^ 1][fk][u] = iv;
                if (t == TS - 1) {
                    out[H0O + (size_t)(row0 + fk)*H0D + u] = hn;
                    out[C0O + (size_t)(row0 + fk)*H0D + u] = c;
                }
            }
            // stage gx(t+2) slice 0 (independent x-MFMAs; fill dep stalls)
            #pragma unroll
            for (int i = 0; i < 5; ++i) {
                const float b = BX[i];
                f32x4 a = {b, b, b, b};
                a = mfma16(xf, WF[32 + i], a);
                *(f32x4*)&gxb[sw][w][i][lane*4] = a;
            }
        }
        lds_barrier();   // B1: LDS-ordered only; vmem stays in flight

        // ========== Phase 2: consumers (waves 4-7) ==========
        if (!prod) {
            const int cw = w - 4;
            // stage gx(t+2) slice 1 for producer wave cw
            #pragma unroll
            for (int i = 0; i < 5; ++i) {
                const float b = BX[i];
                f32x4 a = {b, b, b, b};
                a = mfma16(xf, WF[32 + i], a);
                *(f32x4*)&gxb[sw][cw][5 + i][lane*4] = a;
            }

            // layer1, step t (unchanged from R14)
            bf16x8 pf[4], hq[2];
            #pragma unroll
            for (int ks = 0; ks < 4; ++ks)
                pf[ks] = ld8(&i1f[rp ^ 1][arow][ks*32 + fk*8]);
            #pragma unroll
            for (int k2 = 0; k2 < 2; ++k2)
                hq[k2] = ld8(&h1q[rp][arow][k2*32 + fk*8]);

            const int u1 = cw*16 + fr;
            f32x4 a1[5];
            #pragma unroll
            for (int g = 0; g < 4; ++g) {
                const float b = BZ[g];
                f32x4 a = {b, b, b, b};
                #pragma unroll
                for (int ks = 0; ks < 4; ++ks)
                    a = mfma16(pf[ks], WF[g*6 + ks], a);
                #pragma unroll
                for (int k2 = 0; k2 < 2; ++k2)
                    a = mfma16(hq[k2], WF[g*6 + 4 + k2], a);
                a1[g] = a;
            }
            {
                const float b = BZ[4];
                f32x4 a = {b, b, b, b};
                #pragma unroll
                for (int ks = 0; ks < 4; ++ks)
                    a = mfma16(pf[ks], WF[24 + ks], a);
                a1[4] = a;
            }
            const float i_ = sigm(a1[0][0]);
            const float f_ = sigm(a1[1][0]);
            const float g_ = tanh_f(a1[2][0]);
            const float o_ = sigm(a1[3][0]);
            const float c  = fmaf(f_, CS[0], i_ * g_);
            CS[0] = c;
            const float hn = fmaf(o_, tanh_f(c), a1[4][0]);   // pre-clip state
            const float yv = fminf(fmaxf(hn, -10.f), 10.f);
            out[((size_t)t*BB + row0 + fk)*H1D + u1] = yv;   // store in flight
            h1q[rp ^ 1][fk][u1] = hn;
            if (t == TS - 1) {
                out[H1O + (size_t)(row0 + fk)*H1D + u1] = hn;
                out[C1O + (size_t)(row0 + fk)*H1D + u1] = c;
            }
        }
        st = (st + 1 >= 3) ? 0 : st + 1;
        // no trailing barrier: producer(t+1) writes buffers disjoint from
        // consumer(t) reads; gx slot handoffs fenced per the interval proof.
    }
}

} // namespace

extern "C" void kernel_launch(void* const* d_in, const int* in_sizes, int n_in,
                              void* d_out, int out_size, void* d_ws, size_t ws_size,
                              hipStream_t stream) {
    (void)in_sizes; (void)n_in; (void)d_ws; (void)ws_size; (void)out_size;
    const float* x    = (const float*)d_in[0];
    const float* h0i  = (const float*)d_in[1];
    const float* c0i  = (const float*)d_in[2];
    const float* h1i  = (const float*)d_in[3];
    const float* c1i  = (const float*)d_in[4];
    const float* Wih0 = (const float*)d_in[5];
    const float* Whh0 = (const float*)d_in[6];
    const float* bih0 = (const float*)d_in[7];
    const float* bhh0 = (const float*)d_in[8];
    const float* Ws0  = (const float*)d_in[9];
    const float* bs0  = (const float*)d_in[10];
    const float* Wih1 = (const float*)d_in[11];
    const float* Whh1 = (const float*)d_in[12];
    const float* bih1 = (const float*)d_in[13];
    const float* bhh1 = (const float*)d_in[14];
    const float* Ws1  = (const float*)d_in[15];
    const float* bs1  = (const float*)d_in[16];

    resid_lstm<<<dim3(BB / RPW), dim3(512), 0, stream>>>(
        x, h0i, c0i, h1i, c1i,
        Wih0, Whh0, bih0, bhh0, Ws0, bs0,
        Wih1, Whh1, bih1, bhh1, Ws1, bs1,
        (float*)d_out);
}

// Round 20
// 600.220 us; speedup vs baseline: 8.2378x; 1.0198x over previous
//
#include <hip/hip_runtime.h>
#include <cstdint>
#include <cstddef>

namespace {

constexpr int TS  = 512;   // timesteps
constexpr int BB  = 1024;  // batch
constexpr int IND = 32;    // input dim
constexpr int H0D = 128;   // layer0 hidden
constexpr int H1D = 64;    // layer1 hidden
constexpr int RPW = 4;     // batch rows per WG -> 256 WGs = 1 block/CU
constexpr int S0  = 132;   // padded LDS row stride (floats) for 128-wide state
constexpr int S1  = 68;    // padded LDS row stride (floats) for 64-wide state

typedef float f32x4 __attribute__((ext_vector_type(4)));
typedef __bf16 bf16x8 __attribute__((ext_vector_type(8)));

__device__ __forceinline__ float rcpf(float x) {
    float r; asm("v_rcp_f32 %0, %1" : "=v"(r) : "v"(x)); return r;
}
__device__ __forceinline__ float sigm(float z) { return rcpf(1.0f + __expf(-z)); }
__device__ __forceinline__ float tanh_f(float z) {
    return fmaf(-2.0f, rcpf(__expf(2.0f * z) + 1.0f), 1.0f);  // inf-safe both ends
}
__device__ __forceinline__ bf16x8 cvt8(f32x4 a, f32x4 b) {
    bf16x8 r;
    r[0] = (__bf16)a[0]; r[1] = (__bf16)a[1]; r[2] = (__bf16)a[2]; r[3] = (__bf16)a[3];
    r[4] = (__bf16)b[0]; r[5] = (__bf16)b[1]; r[6] = (__bf16)b[2]; r[7] = (__bf16)b[3];
    return r;
}
__device__ __forceinline__ bf16x8 ld8(const float* p) {
    f32x4 a = *(const f32x4*)p;
    f32x4 b = *(const f32x4*)(p + 4);
    return cvt8(a, b);
}
__device__ __forceinline__ f32x4 mfma16(bf16x8 a, bf16x8 b, f32x4 c) {
    return __builtin_amdgcn_mfma_f32_16x16x32_bf16(a, b, c, 0, 0, 0);
}

// Relaxed barrier: order LDS (lgkmcnt) ONLY; global loads/stores stay in
// flight across the barrier (T4). sched_barrier(0) per rule #18.
__device__ __forceinline__ void lds_barrier() {
    asm volatile("s_waitcnt lgkmcnt(0)" ::: "memory");
    __builtin_amdgcn_s_barrier();
    __builtin_amdgcn_sched_barrier(0);
}

// ===== R14 configuration: best verified (599 us). =====
// 256 WGs x 4 batch rows, 8 waves, 1 block/CU.
// fp32 padded LDS state (one writer lane per dword — bf16 ushort state was
// indicted in R7/R8 via dword-granular write collapse). ONE lds_barrier per
// step: producer waves 0-3 (layer0, 2 slices, step t) write i1f/h0f[rp^1];
// B1; consumer waves 4-7 (layer1 full-K, step t) read i1f[rp^1] while
// producers run ahead into t+1. Distance-2 buffer reuse fenced by B1(t+1)
// (lgkmcnt(0)+s_barrier). x-prefetch and y-stores stay in flight across
// the barrier (no vmcnt drain in the main loop).
// Probe ledger (all within-structure nulls/negatives — R10..R19): bank
// conflicts, vmcnt drain, cvt tax, MFMA-first, occupancy 3w/SIMD, setprio,
// swizzle, P/C rebalance. This is the structure's measured floor.
__global__ __launch_bounds__(512, 2) void resid_lstm(
    const float* __restrict__ x,
    const float* __restrict__ h0i, const float* __restrict__ c0i,
    const float* __restrict__ h1i, const float* __restrict__ c1i,
    const float* __restrict__ Wih0, const float* __restrict__ Whh0,
    const float* __restrict__ bih0, const float* __restrict__ bhh0,
    const float* __restrict__ Ws0,  const float* __restrict__ bs0v,
    const float* __restrict__ Wih1, const float* __restrict__ Whh1,
    const float* __restrict__ bih1, const float* __restrict__ bhh1,
    const float* __restrict__ Ws1,  const float* __restrict__ bs1v,
    float* __restrict__ out)
{
    const int tid  = threadIdx.x;
    const int lane = tid & 63;
    const int w    = tid >> 6;        // wave 0..7
    const int fr   = lane & 15;       // A-row index within tile / C col (unit)
    const int fk   = lane >> 4;       // k-group; also this lane's batch row
    const int row0 = blockIdx.x * RPW;
    const bool prod = (w < 4);

    __shared__ __align__(16) float h0f[2][RPW][S0];   // h0 state (fp32)
    __shared__ __align__(16) float i1f[2][RPW][S0];   // clip(h0) (fp32)
    __shared__ __align__(16) float h1q[2][RPW][S1];   // h1 state (fp32)

    // zero ALL LDS first (separate barrier so init writes can't race it)
    for (int i = tid; i < 2 * RPW * S0; i += 512) {
        (&h0f[0][0][0])[i] = 0.f;
        (&i1f[0][0][0])[i] = 0.f;
    }
    for (int i = tid; i < 2 * RPW * S1; i += 512)
        (&h1q[0][0][0])[i] = 0.f;
    __syncthreads();

    bf16x8 WF[42];    // producer: 42 frags (2 slices x (4 gates x 5 + ws0));
                      // consumer: 28 frags (4 gates x 6 + ws1 x 4)
                      // ONE array for both roles -> allocator overlays storage
                      // (R18 lesson: separate arrays forced the union -> spill)
    float BZ[10];     // folded biases
    float CS[2];      // c-state: producer c0[slice 0,1]; consumer c1 in CS[0]
    CS[0] = 0.f; CS[1] = 0.f;

    if (prod) {
        #pragma unroll
        for (int sl = 0; sl < 2; ++sl) {
            const int u = (w + 4*sl)*16 + fr;
            #pragma unroll
            for (int g = 0; g < 4; ++g) {
                const int r0 = g*H0D + u;             // gate order i,f,g,o
                WF[sl*21 + g*5] = ld8(Wih0 + r0*IND + fk*8);
                #pragma unroll
                for (int ks = 0; ks < 4; ++ks)
                    WF[sl*21 + g*5 + 1 + ks] = ld8(Whh0 + r0*H0D + ks*32 + fk*8);
                BZ[sl*5 + g] = bih0[r0] + bhh0[r0];
            }
            WF[sl*21 + 20] = ld8(Ws0 + u*IND + fk*8);
            BZ[sl*5 + 4] = bs0v[u];
            CS[sl] = c0i[(size_t)(row0 + fk)*H0D + u];
        }
    } else {
        const int u1 = (w - 4)*16 + fr;
        #pragma unroll
        for (int g = 0; g < 4; ++g) {
            const int r1 = g*H1D + u1;
            #pragma unroll
            for (int ks = 0; ks < 4; ++ks)
                WF[g*6 + ks] = ld8(Wih1 + r1*H0D + ks*32 + fk*8);
            #pragma unroll
            for (int k2 = 0; k2 < 2; ++k2)
                WF[g*6 + 4 + k2] = ld8(Whh1 + r1*H1D + k2*32 + fk*8);
            BZ[g] = bih1[r1] + bhh1[r1];
        }
        #pragma unroll
        for (int ks = 0; ks < 4; ++ks)
            WF[24 + ks] = ld8(Ws1 + u1*H0D + ks*32 + fk*8);
        BZ[4] = bs1v[u1];
        CS[0] = c1i[(size_t)(row0 + fk)*H1D + u1];
    }

    // initial hidden states -> LDS fp32 (both read at t=0 from buffer 0)
    {
        const int u = tid & 127, b2 = tid >> 7;
        h0f[0][b2][u] = h0i[(size_t)(row0 + b2)*H0D + u];
    }
    if (tid < RPW * H1D) {
        const int u = tid & 63, b2 = tid >> 6;
        h1q[0][b2][u] = h1i[(size_t)(row0 + b2)*H1D + u];
    }

    const int arow = fr >> 2;   // this lane's A-row batch index (rows duplicated x4)

    const float* xbase = x + ((size_t)row0 + arow)*IND + fk*8;
    f32x4 xa = {0,0,0,0}, xb = {0,0,0,0};
    if (prod) { xa = *(const f32x4*)xbase; xb = *(const f32x4*)(xbase + 4); }

    __syncthreads();

    const size_t H0O = (size_t)TS*BB*H1D;
    const size_t C0O = H0O + (size_t)BB*H0D;
    const size_t H1O = C0O + (size_t)BB*H0D;
    const size_t C1O = H1O + (size_t)BB*H1D;

    #pragma unroll 1
    for (int t = 0; t < TS; ++t) {
        const int rp = t & 1;
        // ========== Phase 1: layer0, step t (waves 0-3) ==========
        if (prod) {
            bf16x8 xf = cvt8(xa, xb);
            {   // prefetch x(t+1); stays in flight across the relaxed barrier
                const int tn = (t + 1 < TS) ? (t + 1) : t;
                const float* xp = xbase + (size_t)tn * (BB*IND);
                xa = *(const f32x4*)xp; xb = *(const f32x4*)(xp + 4);
            }
            bf16x8 hf[4];
            #pragma unroll
            for (int ks = 0; ks < 4; ++ks)
                hf[ks] = ld8(&h0f[rp][arow][ks*32 + fk*8]);

            #pragma unroll
            for (int sl = 0; sl < 2; ++sl) {
                const int u = (w + 4*sl)*16 + fr;
                f32x4 ag[5];
                #pragma unroll
                for (int g = 0; g < 4; ++g) {
                    const float b = BZ[sl*5 + g];
                    f32x4 a = {b, b, b, b};
                    a = mfma16(xf, WF[sl*21 + g*5], a);
                    #pragma unroll
                    for (int ks = 0; ks < 4; ++ks)
                        a = mfma16(hf[ks], WF[sl*21 + g*5 + 1 + ks], a);
                    ag[g] = a;
                }
                {
                    const float b = BZ[sl*5 + 4];
                    f32x4 a = {b, b, b, b};
                    ag[4] = mfma16(xf, WF[sl*21 + 20], a);
                }
                // lane's element: batch row fk (C row 4*fk -> reg 0), unit u
                const float i_ = sigm(ag[0][0]);
                const float f_ = sigm(ag[1][0]);
                const float g_ = tanh_f(ag[2][0]);
                const float o_ = sigm(ag[3][0]);
                const float c  = fmaf(f_, CS[sl], i_ * g_);
                CS[sl] = c;
                const float hn = fmaf(o_, tanh_f(c), ag[4][0]);   // pre-clip state
                const float iv = fminf(fmaxf(hn, -10.f), 10.f);   // layer1 input
                h0f[rp ^ 1][fk][u] = hn;     // fp32 dword: one writer lane each
                i1f[rp ^ 1][fk][u] = iv;
                if (t == TS - 1) {
                    out[H0O + (size_t)(row0 + fk)*H0D + u] = hn;
                    out[C0O + (size_t)(row0 + fk)*H0D + u] = c;
                }
            }
        }
        lds_barrier();   // B1: LDS-ordered only; vmem stays in flight

        // ========== Phase 2: layer1, step t (waves 4-7) ==========
        if (!prod) {
            bf16x8 pf[4], hq[2];
            #pragma unroll
            for (int ks = 0; ks < 4; ++ks)
                pf[ks] = ld8(&i1f[rp ^ 1][arow][ks*32 + fk*8]);
            #pragma unroll
            for (int k2 = 0; k2 < 2; ++k2)
                hq[k2] = ld8(&h1q[rp][arow][k2*32 + fk*8]);

            const int u1 = (w - 4)*16 + fr;
            f32x4 a1[5];
            #pragma unroll
            for (int g = 0; g < 4; ++g) {
                const float b = BZ[g];
                f32x4 a = {b, b, b, b};
                #pragma unroll
                for (int ks = 0; ks < 4; ++ks)
                    a = mfma16(pf[ks], WF[g*6 + ks], a);
                #pragma unroll
                for (int k2 = 0; k2 < 2; ++k2)
                    a = mfma16(hq[k2], WF[g*6 + 4 + k2], a);
                a1[g] = a;
            }
            {
                const float b = BZ[4];
                f32x4 a = {b, b, b, b};
                #pragma unroll
                for (int ks = 0; ks < 4; ++ks)
                    a = mfma16(pf[ks], WF[24 + ks], a);
                a1[4] = a;
            }
            const float i_ = sigm(a1[0][0]);
            const float f_ = sigm(a1[1][0]);
            const float g_ = tanh_f(a1[2][0]);
            const float o_ = sigm(a1[3][0]);
            const float c  = fmaf(f_, CS[0], i_ * g_);
            CS[0] = c;
            const float hn = fmaf(o_, tanh_f(c), a1[4][0]);   // pre-clip state
            const float yv = fminf(fmaxf(hn, -10.f), 10.f);
            out[((size_t)t*BB + row0 + fk)*H1D + u1] = yv;   // store stays in flight
            h1q[rp ^ 1][fk][u1] = hn;
            if (t == TS - 1) {
                out[H1O + (size_t)(row0 + fk)*H1D + u1] = hn;
                out[C1O + (size_t)(row0 + fk)*H1D + u1] = c;
            }
        }
        // no trailing barrier: next step's producer writes land in buffers
        // disjoint from this step's consumer reads; distance-2 reuse is
        // fenced by B1(t+1)'s lgkmcnt(0)+s_barrier.
    }
}

} // namespace

extern "C" void kernel_launch(void* const* d_in, const int* in_sizes, int n_in,
                              void* d_out, int out_size, void* d_ws, size_t ws_size,
                              hipStream_t stream) {
    (void)in_sizes; (void)n_in; (void)d_ws; (void)ws_size; (void)out_size;
    const float* x    = (const float*)d_in[0];
    const float* h0i  = (const float*)d_in[1];
    const float* c0i  = (const float*)d_in[2];
    const float* h1i  = (const float*)d_in[3];
    const float* c1i  = (const float*)d_in[4];
    const float* Wih0 = (const float*)d_in[5];
    const float* Whh0 = (const float*)d_in[6];
    const float* bih0 = (const float*)d_in[7];
    const float* bhh0 = (const float*)d_in[8];
    const float* Ws0  = (const float*)d_in[9];
    const float* bs0  = (const float*)d_in[10];
    const float* Wih1 = (const float*)d_in[11];
    const float* Whh1 = (const float*)d_in[12];
    const float* bih1 = (const float*)d_in[13];
    const float* bhh1 = (const float*)d_in[14];
    const float* Ws1  = (const float*)d_in[15];
    const float* bs1  = (const float*)d_in[16];

    resid_lstm<<<dim3(BB / RPW), dim3(512), 0, stream>>>(
        x, h0i, c0i, h1i, c1i,
        Wih0, Whh0, bih0, bhh0, Ws0, bs0,
        Wih1, Whh1, bih1, bhh1, Ws1, bs1,
        (float*)d_out);
}